// Round 2
// baseline (429.378 us; speedup 1.0000x reference)
//
#include <hip/hip_runtime.h>

// SpMM: out[b,m] = bias[m] + sum_{e: dst[e]==m} values[e] * x[b, src[e]]
// B=32, N=M=50000, E=1600000.
//
// R2 strategy: scatter->gather. Round 1 showed atomicAdd(float) writes through
// to HBM (WRITE_SIZE == E*B*4 = 204.8 MB). Build a dst-CSR per call
// (hist -> scan -> fill of packed {src,val} records), then gather per output
// row with private accumulation. Gather fuses bias + output transpose.

#define BATCH 32

// ---- kernel 1: x (B,N) -> xt (N,B), LDS tiled ----
__global__ void k_transpose_x(const float* __restrict__ x, float* __restrict__ xt, int N) {
    __shared__ float tile[32][33];
    const int n0 = blockIdx.x * 32;
    const int tx = threadIdx.x;   // 0..31
    const int ty = threadIdx.y;   // 0..7
    #pragma unroll
    for (int k = 0; k < 4; ++k) {
        const int b = ty + 8 * k;
        const int n = n0 + tx;
        tile[tx][b] = (n < N) ? x[(size_t)b * N + n] : 0.0f;
    }
    __syncthreads();
    #pragma unroll
    for (int k = 0; k < 4; ++k) {
        const int n = n0 + ty + 8 * k;
        if (n < N) xt[(size_t)n * BATCH + tx] = tile[ty + 8 * k][tx];
    }
}

// ---- kernel 2: histogram of dst ----
__global__ void k_hist(const int* __restrict__ idx, int* __restrict__ counts, int E) {
    const int e = blockIdx.x * blockDim.x + threadIdx.x;
    if (e < E) {
        atomicAdd(&counts[idx[E + e]], 1);
    }
}

// ---- kernel 3: single-block exclusive scan of counts -> row_start, cursor ----
__global__ void k_scan(const int* __restrict__ counts, int* __restrict__ row_start,
                       int* __restrict__ cursor, int M, int E) {
    __shared__ int partial[1024];
    const int t = threadIdx.x;
    const int chunk = (M + 1023) / 1024;
    const int lo = t * chunk;
    const int hi = min(lo + chunk, M);
    int s = 0;
    for (int i = lo; i < hi; ++i) s += counts[i];
    partial[t] = s;
    __syncthreads();
    // Hillis-Steele inclusive scan
    for (int off = 1; off < 1024; off <<= 1) {
        int v = partial[t];
        int add = (t >= off) ? partial[t - off] : 0;
        __syncthreads();
        partial[t] = v + add;
        __syncthreads();
    }
    int base = (t == 0) ? 0 : partial[t - 1];
    for (int i = lo; i < hi; ++i) {
        row_start[i] = base;
        cursor[i]    = base;
        base += counts[i];
    }
    if (t == 0) row_start[M] = E;
}

// ---- kernel 4: fill CSR with packed {src, val} records ----
__global__ void k_fill(const int* __restrict__ idx, const float* __restrict__ values,
                       int* __restrict__ cursor, int2* __restrict__ edges, int E) {
    const int e = blockIdx.x * blockDim.x + threadIdx.x;
    if (e < E) {
        const int src = idx[e];
        const int dst = idx[E + e];
        const float v = values[e];
        const int pos = atomicAdd(&cursor[dst], 1);
        edges[pos] = make_int2(src, __float_as_int(v));
    }
}

// ---- kernel 5: gather + bias + fused output transpose ----
// block = 256 threads = 8 row-slots x 32 batch lanes; 32 rows per block.
__global__ void k_gather(const float* __restrict__ xt, const int2* __restrict__ edges,
                         const int* __restrict__ row_start, const float* __restrict__ bias,
                         float* __restrict__ out, int M) {
    __shared__ float tile[32][33];
    const int m0   = blockIdx.x * 32;
    const int b    = threadIdx.x & 31;
    const int slot = threadIdx.x >> 5;   // 0..7

    #pragma unroll
    for (int rr = 0; rr < 4; ++rr) {
        const int r = slot + rr * 8;     // row within tile
        const int m = m0 + r;
        float acc = 0.0f;
        if (m < M) {
            const int jb = row_start[m];
            const int je = row_start[m + 1];
            acc = bias[m];
            int j = jb;
            for (; j + 2 <= je; j += 2) {
                const int2 e0 = edges[j];
                const int2 e1 = edges[j + 1];
                acc += __int_as_float(e0.y) * xt[(size_t)e0.x * BATCH + b];
                acc += __int_as_float(e1.y) * xt[(size_t)e1.x * BATCH + b];
            }
            if (j < je) {
                const int2 e0 = edges[j];
                acc += __int_as_float(e0.y) * xt[(size_t)e0.x * BATCH + b];
            }
        }
        tile[r][b] = acc;
    }
    __syncthreads();

    // coalesced write-out: out[bb*M + m0+tx]
    const int tx = threadIdx.x & 31;
    #pragma unroll
    for (int pass = 0; pass < 4; ++pass) {
        const int bb = (threadIdx.x >> 5) + pass * 8;
        const int m  = m0 + tx;
        if (m < M) out[(size_t)bb * M + m] = tile[tx][bb];
    }
}

extern "C" void kernel_launch(void* const* d_in, const int* in_sizes, int n_in,
                              void* d_out, int out_size, void* d_ws, size_t ws_size,
                              hipStream_t stream) {
    const float* x      = (const float*)d_in[0];  // (B,N,1) fp32
    const float* values = (const float*)d_in[1];  // (E,)    fp32
    const float* bias   = (const float*)d_in[2];  // (M,1)   fp32
    const int*   idx    = (const int*)d_in[3];    // (2,E)   int32

    const int N = in_sizes[0] / BATCH;   // 50000
    const int E = in_sizes[3] / 2;       // 1600000
    const int M = in_sizes[2];           // 50000

    float* out = (float*)d_out;

    // workspace layout (ws base assumed >=8B aligned):
    //   edges     : E int2          (12.8 MB)
    //   xt        : N*32 float      ( 6.4 MB)
    //   counts    : M int           ( 0.2 MB)
    //   row_start : M+1 int
    //   cursor    : M int
    char* p = (char*)d_ws;
    int2* edges     = (int2*)p;                 p += (size_t)E * sizeof(int2);
    float* xt       = (float*)p;                p += (size_t)N * BATCH * sizeof(float);
    int* counts     = (int*)p;                  p += (size_t)M * sizeof(int);
    int* row_start  = (int*)p;                  p += (size_t)(M + 1) * sizeof(int);
    int* cursor     = (int*)p;

    hipMemsetAsync(counts, 0, (size_t)M * sizeof(int), stream);

    dim3 tblk(32, 8);
    k_transpose_x<<<(N + 31) / 32, tblk, 0, stream>>>(x, xt, N);

    const int eg = (E + 255) / 256;
    k_hist<<<eg, 256, 0, stream>>>(idx, counts, E);
    k_scan<<<1, 1024, 0, stream>>>(counts, row_start, cursor, M, E);
    k_fill<<<eg, 256, 0, stream>>>(idx, values, cursor, edges, E);
    k_gather<<<(M + 31) / 32, 256, 0, stream>>>(xt, edges, row_start, bias, out, M);
}